// Round 12
// baseline (1061.737 us; speedup 1.0000x reference)
//
#include <hip/hip_runtime.h>

// MultiTaskVQAModel: v/q projections -> Mutan fusion (rank 15) -> per-question-type heads.
// Round 12: merged phases in gemm256_dual — 2 phases/K-tile of 32 MFMA each (was 4x16),
// halving s_barrier count. vmcnt(8)-before-BAR pattern retained (cross-wave residency:
// each wave drains own loads pre-barrier; kh0(t) is 2 wait-points old, kh1(t) is 1).
// af[8]+bf[4] live intra-phase only: ~112 VGPR + 128 AGPR = 240 <= 256 granule, no spill.

using u16 = unsigned short;
typedef __bf16 b16x8 __attribute__((ext_vector_type(8)));
typedef float f32x4 __attribute__((ext_vector_type(4)));
typedef unsigned u32x4 __attribute__((ext_vector_type(4)));

static __device__ __forceinline__ u16 f2bf(float f) {
  unsigned int u = __builtin_bit_cast(unsigned int, f);
  u = (u + 0x7fffu + ((u >> 16) & 1u)) >> 16;   // round-to-nearest-even
  return (u16)u;
}
static __device__ __forceinline__ float bf2f(u16 h) {
  return __builtin_bit_cast(float, (unsigned int)h << 16);
}

static __device__ __forceinline__ void gload_lds16(const u16* g, u16* l) {
  __builtin_amdgcn_global_load_lds((__attribute__((address_space(1))) void*)(g),
                                   (__attribute__((address_space(3))) void*)(l), 16, 0, 0);
}

// LDS tiles: [rows][4 slots of 8 bf16]; linear slot s holds global slot s ^ ((row>>1)&3).
static __device__ __forceinline__ int lds_off(int row, int slot) {
  return row * 32 + ((slot ^ ((row >> 1) & 3)) << 3);
}

// ---------------- conversion / padding kernels ----------------

struct CvtJobs {
  const float* s[4];
  u16* d[4];
  int Ns[4], Ks[4], Nd[4], Kd[4];
};

// multi-job f32 -> padded bf16 [Nd,Kd]; job = blockIdx.y; Kd % 8 == 0.
__global__ __launch_bounds__(256) void cvtN_kernel(CvtJobs J) {
  const int jb = blockIdx.y;
  const int Ns = J.Ns[jb], Ks = J.Ks[jb], Kd = J.Kd[jb];
  long long idx = (long long)blockIdx.x * blockDim.x + threadIdx.x;
  long long total = ((long long)J.Nd[jb] * Kd) >> 3;
  if (idx >= total) return;
  const float* __restrict__ src = J.s[jb];
  u16* __restrict__ dst = J.d[jb];
  long long e = idx << 3;
  int r = (int)(e / Kd);
  int c = (int)(e - (long long)r * Kd);
  u16 v[8];
  if (r < Ns && c + 8 <= Ks) {
    const float* s = src + (long long)r * Ks + c;
#pragma unroll
    for (int i = 0; i < 8; ++i) v[i] = f2bf(s[i]);
  } else {
#pragma unroll
    for (int i = 0; i < 8; ++i) {
      int cc = c + i;
      float f = (r < Ns && cc < Ks) ? src[(long long)r * Ks + cc] : 0.f;
      v[i] = f2bf(f);
    }
  }
  uint4 o;
  o.x = (unsigned)v[0] | ((unsigned)v[1] << 16);
  o.y = (unsigned)v[2] | ((unsigned)v[3] << 16);
  o.z = (unsigned)v[4] | ((unsigned)v[5] << 16);
  o.w = (unsigned)v[6] | ((unsigned)v[7] << 16);
  *reinterpret_cast<uint4*>(dst + e) = o;
}

struct PadJobs {
  const float* s[9];
  float* d[9];
  int ns[9];
  int nd[9];
};
__global__ __launch_bounds__(256) void pad_all_kernel(PadJobs pj) {
  const int job = blockIdx.y;
  const int i = blockIdx.x * 256 + threadIdx.x;
  if (i < pj.nd[job]) pj.d[job][i] = (i < pj.ns[job]) ? pj.s[job][i] : 0.f;
}

// ---------------- generic bf16 GEMM (128x128, 2-phase), dual-operand via blockIdx.z ----------------
template <int TANH, int OUT_BF16>
__global__ __launch_bounds__(256) void gemm_bt_kernel(
    const u16* __restrict__ A0, const u16* __restrict__ B0,
    const float* __restrict__ bias0, void* __restrict__ C0v, int K0,
    const u16* __restrict__ A1, const u16* __restrict__ B1,
    const float* __restrict__ bias1, void* __restrict__ C1v, int K1,
    int Nout, int Nfill, int ldc) {
  __shared__ u16 sA[128 * 32];
  __shared__ u16 sB[128 * 32];
  const int z = blockIdx.z;
  const u16* A = z ? A1 : A0;
  const u16* B = z ? B1 : B0;
  const float* bias = z ? bias1 : bias0;
  void* Cv = z ? C1v : C0v;
  const int K = z ? K1 : K0;
  const int tid = threadIdx.x;
  const int wid = tid >> 6;
  const int lane = tid & 63;
  const long long brow = (long long)blockIdx.y * 128;
  const long long bcol = (long long)blockIdx.x * 128;
  const int wr = (wid >> 1) * 64;
  const int wc = (wid & 1) * 64;
  const int lr = lane & 15;
  const int slot = lane >> 4;

  f32x4 acc[4][4];
#pragma unroll
  for (int i = 0; i < 4; ++i)
#pragma unroll
    for (int j = 0; j < 4; ++j)
#pragma unroll
      for (int q = 0; q < 4; ++q) acc[i][j][q] = 0.f;

  for (int k0 = 0; k0 < K; k0 += 32) {
    __syncthreads();
#pragma unroll
    for (int j = 0; j < 2; ++j) {
      const int c = j * 256 + tid;
      const int r = c >> 2;
      const int kc = ((c & 3) ^ ((r >> 1) & 3)) * 8;   // pre-swizzled source
      gload_lds16(A + (brow + r) * K + k0 + kc, sA + c * 8);
      gload_lds16(B + (bcol + r) * K + k0 + kc, sB + c * 8);
    }
    __syncthreads();
    b16x8 af[4], bfr[4];
#pragma unroll
    for (int i = 0; i < 4; ++i) {
      af[i]  = *reinterpret_cast<const b16x8*>(&sA[lds_off(wr + i * 16 + lr, slot)]);
      bfr[i] = *reinterpret_cast<const b16x8*>(&sB[lds_off(wc + i * 16 + lr, slot)]);
    }
#pragma unroll
    for (int i = 0; i < 4; ++i)
#pragma unroll
      for (int j = 0; j < 4; ++j)
        acc[i][j] = __builtin_amdgcn_mfma_f32_16x16x32_bf16(af[i], bfr[j], acc[i][j], 0, 0, 0);
  }

  const int rbase = wr + (lane >> 4) * 4;
#pragma unroll
  for (int i = 0; i < 4; ++i) {
#pragma unroll
    for (int j = 0; j < 4; ++j) {
      const long long col = bcol + wc + j * 16 + lr;
      if (col < Nfill) {
        const float bb = (col < Nout) ? bias[col] : 0.f;
#pragma unroll
        for (int q = 0; q < 4; ++q) {
          float v = acc[i][j][q] + bb;
          if (TANH) v = tanhf(v);
          if (col >= Nout) v = 0.f;
          const long long row = brow + rbase + i * 16 + q;
          if (OUT_BF16)
            reinterpret_cast<u16*>(Cv)[row * ldc + col] = f2bf(v);
          else
            reinterpret_cast<float*>(Cv)[row * ldc + col] = v;
        }
      }
    }
  }
}

// ---------------- 256x256 dual GEMM, 2 merged phases/K-tile, bf16 out ----------------
// C = A @ B^T + bias (bf16). blockIdx.z (post-swizzle) selects pair. Nout % 64 == 0.
// 8 waves (2M x 4N), BK=64, K-half-major LDS, dbuf, counted vmcnt(8), XCD swizzle.
// Each phase: 12 ds_reads + stage(A,B) + BAR + 32 MFMA + vmcnt(8) + BAR.
// Residency: kh0(t) staged (t-2)phB = 2 wait-points old; kh1(t) staged (t-1)phA = 1 old.
template <int TANH, int NTST>
__global__ __launch_bounds__(512, 2) void gemm256_dual_kernel(
    const u16* __restrict__ A0, const u16* __restrict__ Bg0,
    const float* __restrict__ bias0, u16* __restrict__ C0,
    const u16* __restrict__ A1, const u16* __restrict__ Bg1,
    const float* __restrict__ bias1, u16* __restrict__ C1,
    int K, int Nout, int ldc) {
  __shared__ u16 sAB[65536];
  const int tid = threadIdx.x;
  const int lane = tid & 63;
  const int wid = tid >> 6;
  const int wm = wid >> 2;
  const int wn = wid & 3;

  // XCD-aware bijective swizzle (nwg % 8 == 0 by construction).
  const int gy = gridDim.y;
  const int nwg = 16 * gy * gridDim.z;
  int flat = blockIdx.x + 16 * (blockIdx.y + gy * blockIdx.z);
  flat = (flat & 7) * (nwg >> 3) + (flat >> 3);
  const int m = flat & 15;
  const int rest = flat >> 4;
  const int n = rest % gy;
  const int z = rest / gy;

  const long long brow = (long long)m * 256;
  const long long bcol = (long long)n * 256;
  const u16* Ag = z ? A1 : A0;
  const u16* Bg = z ? Bg1 : Bg0;
  const float* bias = z ? bias1 : bias0;
  u16* C = z ? C1 : C0;
  const int nt = K >> 6;

  auto stage = [&](int isB, int buf, int kh, int kbase) {
    const u16* G = isB ? Bg : Ag;
    const long long rbase = isB ? bcol : brow;
    u16* ldst = &sAB[(isB ? 32768 : 0) + buf * 16384 + kh * 8192 + tid * 8];
#pragma unroll
    for (int rh = 0; rh < 2; ++rh) {
      const int row = rh * 128 + (tid >> 2);
      const int gcol = kbase + kh * 32 + (((tid & 3) ^ ((row >> 1) & 3)) << 3);
      gload_lds16(G + (rbase + row) * K + gcol, ldst + rh * 4096);
    }
  };
  auto rdA = [&](int buf, int fr, int ksub) {
    const int row = wm * 128 + fr * 16 + (lane & 15);
    return *reinterpret_cast<const b16x8*>(
        &sAB[buf * 16384 + ksub * 8192 + lds_off(row, lane >> 4)]);
  };
  auto rdB = [&](int buf, int fj, int ksub) {
    const int row = wn * 64 + fj * 16 + (lane & 15);
    return *reinterpret_cast<const b16x8*>(
        &sAB[32768 + buf * 16384 + ksub * 8192 + lds_off(row, lane >> 4)]);
  };

  f32x4 acc[8][4];
#pragma unroll
  for (int i = 0; i < 8; ++i)
#pragma unroll
    for (int j = 0; j < 4; ++j)
#pragma unroll
      for (int q = 0; q < 4; ++q) acc[i][j][q] = 0.f;

  // prologue: tile0 fully + tile1 khalf0; wait for tile0 (8 oldest of 12).
  stage(0, 0, 0, 0); stage(1, 0, 0, 0); stage(0, 0, 1, 0); stage(1, 0, 1, 0);
  stage(0, 1, 0, 64); stage(1, 1, 0, 64);
  asm volatile("s_waitcnt vmcnt(4)" ::: "memory");
  __builtin_amdgcn_s_barrier();

  b16x8 af[8], bf[4];
  for (int t = 0; t < nt; ++t) {
    const int cur = t & 1;
    const int kn1 = (t + 1) << 6, kn2 = (t + 2) << 6;
    if (t + 1 == nt) {  // final tile: no more prefetch -> drain everything.
      asm volatile("s_waitcnt vmcnt(0)" ::: "memory");
      __builtin_amdgcn_s_barrier();
    }
    // ---- phase A: all rows, ksub 0 ----
#pragma unroll
    for (int j = 0; j < 4; ++j) bf[j] = rdB(cur, j, 0);
#pragma unroll
    for (int i = 0; i < 8; ++i) af[i] = rdA(cur, i, 0);
    if (t + 1 < nt) {
      stage(0, cur ^ 1, 1, kn1);                      // A-kh1(t+1)
      stage(1, cur ^ 1, 1, kn1);                      // B-kh1(t+1)
    }
    __builtin_amdgcn_s_barrier();
    __builtin_amdgcn_s_setprio(1);
#pragma unroll
    for (int i = 0; i < 8; ++i)
#pragma unroll
      for (int j = 0; j < 4; ++j)
        acc[i][j] = __builtin_amdgcn_mfma_f32_16x16x32_bf16(af[i], bf[j], acc[i][j], 0, 0, 0);
    __builtin_amdgcn_s_setprio(0);
    asm volatile("s_waitcnt vmcnt(8)" ::: "memory");  // kh1(t) (staged (t-1)phA) complete
    __builtin_amdgcn_s_barrier();
    // ---- phase B: all rows, ksub 1 ----
#pragma unroll
    for (int j = 0; j < 4; ++j) bf[j] = rdB(cur, j, 1);
#pragma unroll
    for (int i = 0; i < 8; ++i) af[i] = rdA(cur, i, 1);
    if (t + 2 < nt) {
      stage(0, cur, 0, kn2);                          // A-kh0(t+2)
      stage(1, cur, 0, kn2);                          // B-kh0(t+2)
    }
    __builtin_amdgcn_s_barrier();
    __builtin_amdgcn_s_setprio(1);
#pragma unroll
    for (int i = 0; i < 8; ++i)
#pragma unroll
      for (int j = 0; j < 4; ++j)
        acc[i][j] = __builtin_amdgcn_mfma_f32_16x16x32_bf16(af[i], bf[j], acc[i][j], 0, 0, 0);
    __builtin_amdgcn_s_setprio(0);
    asm volatile("s_waitcnt vmcnt(8)" ::: "memory");  // kh0(t+1) (staged (t-1)phB) complete
    __builtin_amdgcn_s_barrier();
  }

  // epilogue: per-wave padded LDS bounce (stride 68 f32) -> bf16 full-line stores.
  __syncthreads();
  const long long gcb = bcol + wn * 64;
  float* lp = reinterpret_cast<float*>(sAB) + wid * 1104;
  if (gcb < Nout) {
    float bv4[4];
#pragma unroll
    for (int j = 0; j < 4; ++j) bv4[j] = bias[gcb + j * 16 + (lane & 15)];
#pragma unroll
    for (int fr = 0; fr < 8; ++fr) {
#pragma unroll
      for (int j = 0; j < 4; ++j)
#pragma unroll
        for (int q = 0; q < 4; ++q)
          lp[((lane >> 4) * 4 + q) * 68 + j * 16 + (lane & 15)] = acc[fr][j][q] + bv4[j];
#pragma unroll
      for (int p = 0; p < 2; ++p) {
        const int row = p * 8 + (lane >> 3);
        float f[8];
        *reinterpret_cast<float4*>(&f[0]) =
            *reinterpret_cast<const float4*>(&lp[row * 68 + (lane & 7) * 8]);
        *reinterpret_cast<float4*>(&f[4]) =
            *reinterpret_cast<const float4*>(&lp[row * 68 + (lane & 7) * 8 + 4]);
        if (TANH) {
#pragma unroll
          for (int k = 0; k < 8; ++k) f[k] = tanhf(f[k]);
        }
        u32x4 o;
        o.x = (unsigned)f2bf(f[0]) | ((unsigned)f2bf(f[1]) << 16);
        o.y = (unsigned)f2bf(f[2]) | ((unsigned)f2bf(f[3]) << 16);
        o.z = (unsigned)f2bf(f[4]) | ((unsigned)f2bf(f[5]) << 16);
        o.w = (unsigned)f2bf(f[6]) | ((unsigned)f2bf(f[7]) << 16);
        const long long grow = brow + wm * 128 + fr * 16 + row;
        u32x4* dst = reinterpret_cast<u32x4*>(&C[grow * ldc + gcb + (lane & 7) * 8]);
        if (NTST)
          __builtin_nontemporal_store(o, dst);
        else
          *dst = o;
      }
    }
  }
}

// ---------------- rank product + partial sum (bf16 M inputs, NT loads) ----------------
// EMITB: final chunk — z = ZF_prev + acc, emitted directly as bf16 into ZB.
template <int FIRST, int EMITB>
__global__ __launch_bounds__(256) void rank_mul_kernel(
    const u16* __restrict__ M0, const u16* __restrict__ M1,
    float* __restrict__ ZF, u16* __restrict__ ZB, int rc, int ldm) {
  const int idx = blockIdx.x * 256 + threadIdx.x;     // 4096*200 threads
  const int b = idx / 200;
  const int d0 = (idx - b * 200) * 8;
  const u16* p0 = M0 + (long long)b * ldm + d0;
  const u16* p1 = M1 + (long long)b * ldm + d0;
  float acc[8];
#pragma unroll
  for (int i = 0; i < 8; ++i) acc[i] = 0.f;
  for (int r = 0; r < rc; ++r) {
    const u32x4 a = __builtin_nontemporal_load(reinterpret_cast<const u32x4*>(p0 + r * 1600));
    const u32x4 c = __builtin_nontemporal_load(reinterpret_cast<const u32x4*>(p1 + r * 1600));
    const unsigned aw[4] = {a.x, a.y, a.z, a.w};
    const unsigned cw[4] = {c.x, c.y, c.z, c.w};
#pragma unroll
    for (int k = 0; k < 4; ++k) {
      acc[2 * k]     += bf2f((u16)(aw[k] & 0xffff)) * bf2f((u16)(cw[k] & 0xffff));
      acc[2 * k + 1] += bf2f((u16)(aw[k] >> 16))    * bf2f((u16)(cw[k] >> 16));
    }
  }
  float* zf = ZF + (long long)b * 1600 + d0;
  if (EMITB) {
#pragma unroll
    for (int i = 0; i < 8; ++i) acc[i] += zf[i];
    uint4 o;
    o.x = (unsigned)f2bf(acc[0]) | ((unsigned)f2bf(acc[1]) << 16);
    o.y = (unsigned)f2bf(acc[2]) | ((unsigned)f2bf(acc[3]) << 16);
    o.z = (unsigned)f2bf(acc[4]) | ((unsigned)f2bf(acc[5]) << 16);
    o.w = (unsigned)f2bf(acc[6]) | ((unsigned)f2bf(acc[7]) << 16);
    *reinterpret_cast<uint4*>(ZB + (long long)b * 1600 + d0) = o;
  } else if (FIRST) {
#pragma unroll
    for (int i = 0; i < 8; ++i) zf[i] = acc[i];
  } else {
#pragma unroll
    for (int i = 0; i < 8; ++i) zf[i] += acc[i];
  }
}

// ---------------- per-row head: layer2 + slice/mask assembly ----------------
__global__ __launch_bounds__(256) void head_kernel(
    const float* __restrict__ T, const int* __restrict__ qtype,
    const float* __restrict__ W20, const float* __restrict__ b20,
    const float* __restrict__ W21, const float* __restrict__ b21,
    const float* __restrict__ W22, const float* __restrict__ b22,
    const float* __restrict__ W23, const float* __restrict__ b23,
    float* __restrict__ out) {
  const int b = blockIdx.x * 4 + (threadIdx.x >> 6);
  const int lane = threadIdx.x & 63;
  const int qt = qtype[b];
  const float* W2 = (qt == 0) ? W20 : (qt == 1) ? W21 : (qt == 2) ? W22 : W23;
  const float* b2 = (qt == 0) ? b20 : (qt == 1) ? b21 : (qt == 2) ? b22 : b23;
  const int lo = (qt == 2) ? 2 : (qt == 3) ? 7 : 0;
  const int hi = (qt == 3) ? 95 : (qt == 2) ? 7 : 2;
  const float* trow = T + (long long)b * 1024 + qt * 256;
  for (int c = lane; c < 95; c += 64) {
    float v = 0.f;
    if (c >= lo && c < hi) {
      const int jj = c - lo;
      const float* w = W2 + jj * 256;
      float acc = b2[jj];
      for (int k = 0; k < 256; k += 4) {
        const float4 tv = *reinterpret_cast<const float4*>(trow + k);
        const float4 wv = *reinterpret_cast<const float4*>(w + k);
        acc += tv.x * wv.x + tv.y * wv.y + tv.z * wv.z + tv.w * wv.w;
      }
      v = acc;
    }
    out[(long long)b * 95 + c] = v;
  }
}

// ---------------- launch ----------------

extern "C" void kernel_launch(void* const* d_in, const int* in_sizes, int n_in,
                              void* d_out, int out_size, void* d_ws, size_t ws_size,
                              hipStream_t stream) {
  (void)in_sizes; (void)n_in; (void)out_size; (void)ws_size;
  const float* input_v = (const float*)d_in[0];
  const float* input_q = (const float*)d_in[1];
  const int*   qtype   = (const int*)d_in[2];
  const float* Wv  = (const float*)d_in[3];  const float* bv  = (const float*)d_in[4];
  const float* Wq  = (const float*)d_in[5];  const float* bq  = (const float*)d_in[6];
  const float* W0  = (const float*)d_in[7];  const float* b0  = (const float*)d_in[8];
  const float* W1  = (const float*)d_in[9];  const float* b1  = (const float*)d_in[10];
  const float* Wm0 = (const float*)d_in[11]; const float* bm0 = (const float*)d_in[12];
  const float* Wm1 = (const float*)d_in[13]; const float* bm1 = (const float*)d_in[14];
  const float* Wo  = (const float*)d_in[15]; const float* bo  = (const float*)d_in[16];
  const float* cW1[4] = {(const float*)d_in[17], (const float*)d_in[21],
                         (const float*)d_in[25], (const float*)d_in[29]};
  const float* cb1[4] = {(const float*)d_in[18], (const float*)d_in[22],
                         (const float*)d_in[26], (const float*)d_in[30]};
  const float* cW2[4] = {(const float*)d_in[19], (const float*)d_in[23],
                         (const float*)d_in[27], (const float*)d_in[31]};
  const float* cb2[4] = {(const float*)d_in[20], (const float*)d_in[24],
                         (const float*)d_in[28], (const float*)d_in[32]};

  char* ws = (char*)d_ws;
  // Persistent across stage 4: H0, H1, ZF.
  u16*   H0  = (u16*)(ws + 0);           // [4096,1600] bf16
  u16*   H1  = (u16*)(ws + 13107200);    // [4096,1600] bf16
  float* ZF  = (float*)(ws + 26214400);  // [4096,1600] f32 accumulator
  char*  S   = ws + 52428800;            // overlay region
  // stages 1-3
  u16*   XV  = (u16*)(S + 0);            // [4096,1216]
  u16*   XQ  = (u16*)(S + 9961472);      // [4096,1216]
  char*  S3  = S + 19922944;             // cvt buffers
  // stage 4 chunk buffers (XV/XQ dead by then): 5-rank chunks (cols=8000, pad 8192)
  u16*   WMC0 = (u16*)(S + 0);           // [8192,1600] bf16 = 26.2 MB
  u16*   WMC1 = (u16*)(S + 26214400);
  u16*   M0C  = (u16*)(S + 52428800);    // [4096,8000] bf16 = 65.5 MB
  u16*   M1C  = (u16*)(S + 117964800);   // ends S+183,500,800 = ws+235.93 MB
  // stages 5-7
  u16*   ZB  = (u16*)(S + 0);            // [4096,1600] bf16
  u16*   XB  = (u16*)(S + 13107200);     // [4096,1216] bf16
  float* TB  = (float*)(S + 23068672);   // [4096,1024] f32
  char*  S5  = S + 39845888;
  // biases (above stage-4 overlay; ws usage ends < 236.15 MB, proven safe 239.6 MB)
  float* BVP = (float*)(ws + 236100000); // [1280]
  float* BQP = (float*)(ws + 236105120);
  float* B0P = (float*)(ws + 236110240); // [1664]
  float* B1P = (float*)(ws + 236116896);
  float* BOP = (float*)(ws + 236123552); // [1280]
  float* B1C = (float*)(ws + 236128672); // [1024]

  const dim3 blk(256);
  auto blocks8 = [](long long n, int kd) {  // grid.x for one cvt job
    return (unsigned)((((long long)n * kd) >> 3) + 255) / 256;
  };
  auto cvt2 = [&](const float* s0, u16* d0, int Ns0, int Ks0, int Nd0, int Kd0,
                  const float* s1, u16* d1, int Ns1, int Ks1, int Nd1, int Kd1) {
    CvtJobs J;
    J.s[0] = s0; J.d[0] = d0; J.Ns[0] = Ns0; J.Ks[0] = Ks0; J.Nd[0] = Nd0; J.Kd[0] = Kd0;
    J.s[1] = s1; J.d[1] = d1; J.Ns[1] = Ns1; J.Ks[1] = Ks1; J.Nd[1] = Nd1; J.Kd[1] = Kd1;
    J.s[2] = s1; J.d[2] = d1; J.Ns[2] = 0; J.Ks[2] = Ks1; J.Nd[2] = 0; J.Kd[2] = Kd1;
    J.s[3] = J.s[2]; J.d[3] = J.d[2]; J.Ns[3] = 0; J.Ks[3] = Ks1; J.Nd[3] = 0; J.Kd[3] = Kd1;
    unsigned gx = blocks8(Nd0, Kd0);
    unsigned gx1 = blocks8(Nd1, Kd1);
    if (gx1 > gx) gx = gx1;
    cvtN_kernel<<<dim3(gx, 2), blk, 0, stream>>>(J);
  };

  // all bias pads in one launch
  {
    PadJobs pj;
    const float* ss[9] = {bv, bq, b0, b1, bo, cb1[0], cb1[1], cb1[2], cb1[3]};
    float* dd[9] = {BVP, BQP, B0P, B1P, BOP, B1C, B1C + 256, B1C + 512, B1C + 768};
    int nss[9] = {1200, 1200, 1600, 1600, 1200, 256, 256, 256, 256};
    int ndd[9] = {1280, 1280, 1664, 1664, 1280, 256, 256, 256, 256};
    for (int i = 0; i < 9; ++i) { pj.s[i] = ss[i]; pj.d[i] = dd[i]; pj.ns[i] = nss[i]; pj.nd[i] = ndd[i]; }
    pad_all_kernel<<<dim3(7, 9), blk, 0, stream>>>(pj);
  }

  // stages 1+2 fused: x_v = tanh(input_v @ Wv^T + bv); x_q = tanh(input_q @ Wq^T + bq)
  {
    u16* INV = (u16*)S3;                     // [4096,768]
    u16* WVB = (u16*)(S3 + 6291456);         // [1280,768]
    u16* INQ = (u16*)(S3 + 8257536);         // [4096,2400] (19.66 MB)
    u16* WQB = (u16*)(S3 + 27918336);        // [1280,2400] (6.14 MB; ends S3+34.06MB)
    cvt2(input_v, INV, 4096, 768, 4096, 768,
         input_q, INQ, 4096, 2400, 4096, 2400);
    cvt2(Wv, WVB, 1200, 768, 1280, 768,
         Wq, WQB, 1200, 2400, 1280, 2400);
    gemm_bt_kernel<1, 1><<<dim3(10, 32, 2), blk, 0, stream>>>(
        INV, WVB, BVP, XV, 768,
        INQ, WQB, BQP, XQ, 2400, 1200, 1216, 1216);
  }
  // stage 3: h0 = x_v @ W0^T + b0 ; h1 = x_q @ W1^T + b1  (256^2 dual, K=1216, nt=19)
  {
    u16* W0B = (u16*)S3;                     // [1792,1216]
    u16* W1B = (u16*)(S3 + 4358144);
    cvt2(W0, W0B, 1600, 1200, 1792, 1216,
         W1, W1B, 1600, 1200, 1792, 1216);
    gemm256_dual_kernel<0, 0><<<dim3(16, 7, 2), dim3(512), 0, stream>>>(
        XV, W0B, B0P, H0, XQ, W1B, B1P, H1, 1216, 1600, 1600);
  }
  // stage 4: Mutan via 3 chunks x 5 ranks (cols=8000, NB=32 -> 1024 blocks = 4 full rounds).
  for (int c = 0; c < 3; ++c) {
    const int cols = 8000;
    const int NB = 32;                       // pad to 8192
    const int rowsPad = 8192;
    const long long roff = (long long)c * 8000;
    cvt2(Wm0 + roff * 1600, WMC0, cols, 1600, rowsPad, 1600,
         Wm1 + roff * 1600, WMC1, cols, 1600, rowsPad, 1600);
    gemm256_dual_kernel<0, 1><<<dim3(16, NB, 2), dim3(512), 0, stream>>>(
        H0, WMC0, bm0 + roff, M0C, H1, WMC1, bm1 + roff, M1C, 1600, cols, cols);
    if (c == 0)
      rank_mul_kernel<1, 0><<<dim3(3200), blk, 0, stream>>>(M0C, M1C, ZF, ZB, 5, cols);
    else if (c == 1)
      rank_mul_kernel<0, 0><<<dim3(3200), blk, 0, stream>>>(M0C, M1C, ZF, ZB, 5, cols);
    else
      rank_mul_kernel<0, 1><<<dim3(3200), blk, 0, stream>>>(M0C, M1C, ZF, ZB, 5, cols);
  }
  // stage 5: x = z @ Wo^T + bo
  {
    u16* WOB = (u16*)S5;                     // [1280,1600]
    cvt2(Wo, WOB, 1200, 1600, 1280, 1600,
         Wo, WOB, 0, 1600, 0, 1600);         // job1 degenerate (0 rows)
    gemm_bt_kernel<0, 1><<<dim3(10, 32, 1), blk, 0, stream>>>(
        ZB, WOB, BOP, XB, 1600,
        ZB, WOB, BOP, XB, 1600, 1200, 1216, 1216);
  }
  // stage 6: t = tanh(x @ cW1cat^T + b1cat), all 4 heads batched (N=1024)
  {
    u16* CW1B = (u16*)S5;                    // [1024,1216]
    CvtJobs J;
    for (int qt = 0; qt < 4; ++qt) {
      J.s[qt] = cW1[qt];
      J.d[qt] = CW1B + (long long)qt * 256 * 1216;
      J.Ns[qt] = 256; J.Ks[qt] = 1200; J.Nd[qt] = 256; J.Kd[qt] = 1216;
    }
    cvtN_kernel<<<dim3(blocks8(256, 1216), 4), blk, 0, stream>>>(J);
    gemm_bt_kernel<1, 0><<<dim3(8, 32, 1), blk, 0, stream>>>(
        XB, CW1B, B1C, TB, 1216,
        XB, CW1B, B1C, TB, 1216, 1024, 1024, 1024);
  }
  // stage 7: layer2 + assemble final [4096,95]
  head_kernel<<<dim3(1024), blk, 0, stream>>>(TB, qtype,
      cW2[0], cb2[0], cW2[1], cb2[1], cW2[2], cb2[2], cW2[3], cb2[3],
      (float*)d_out);
}

// Round 13
// 1048.791 us; speedup vs baseline: 1.0123x; 1.0123x over previous
//
#include <hip/hip_runtime.h>

// MultiTaskVQAModel: v/q projections -> Mutan fusion (rank 15) -> per-question-type heads.
// Round 13: surgical staging-pointer hoist in gemm256_dual — global staging addresses are
// 4 loop-carried pointer pairs advanced +32 elems/stage (A-stage k-seq 0,32,64,... exactly
// arithmetic), replacing per-call 64-bit (rbase+row)*K math (~40 VALU/phase on the
// pre-barrier critical path). Everything else byte-identical to round 12 (which proved
// +8 transient regs safe; r6's spill came from the macro unroll, not the hoist).

using u16 = unsigned short;
typedef __bf16 b16x8 __attribute__((ext_vector_type(8)));
typedef float f32x4 __attribute__((ext_vector_type(4)));
typedef unsigned u32x4 __attribute__((ext_vector_type(4)));

static __device__ __forceinline__ u16 f2bf(float f) {
  unsigned int u = __builtin_bit_cast(unsigned int, f);
  u = (u + 0x7fffu + ((u >> 16) & 1u)) >> 16;   // round-to-nearest-even
  return (u16)u;
}
static __device__ __forceinline__ float bf2f(u16 h) {
  return __builtin_bit_cast(float, (unsigned int)h << 16);
}

static __device__ __forceinline__ void gload_lds16(const u16* g, u16* l) {
  __builtin_amdgcn_global_load_lds((__attribute__((address_space(1))) void*)(g),
                                   (__attribute__((address_space(3))) void*)(l), 16, 0, 0);
}

// LDS tiles: [rows][4 slots of 8 bf16]; linear slot s holds global slot s ^ ((row>>1)&3).
static __device__ __forceinline__ int lds_off(int row, int slot) {
  return row * 32 + ((slot ^ ((row >> 1) & 3)) << 3);
}

// ---------------- conversion / padding kernels ----------------

struct CvtJobs {
  const float* s[4];
  u16* d[4];
  int Ns[4], Ks[4], Nd[4], Kd[4];
};

// multi-job f32 -> padded bf16 [Nd,Kd]; job = blockIdx.y; Kd % 8 == 0.
__global__ __launch_bounds__(256) void cvtN_kernel(CvtJobs J) {
  const int jb = blockIdx.y;
  const int Ns = J.Ns[jb], Ks = J.Ks[jb], Kd = J.Kd[jb];
  long long idx = (long long)blockIdx.x * blockDim.x + threadIdx.x;
  long long total = ((long long)J.Nd[jb] * Kd) >> 3;
  if (idx >= total) return;
  const float* __restrict__ src = J.s[jb];
  u16* __restrict__ dst = J.d[jb];
  long long e = idx << 3;
  int r = (int)(e / Kd);
  int c = (int)(e - (long long)r * Kd);
  u16 v[8];
  if (r < Ns && c + 8 <= Ks) {
    const float* s = src + (long long)r * Ks + c;
#pragma unroll
    for (int i = 0; i < 8; ++i) v[i] = f2bf(s[i]);
  } else {
#pragma unroll
    for (int i = 0; i < 8; ++i) {
      int cc = c + i;
      float f = (r < Ns && cc < Ks) ? src[(long long)r * Ks + cc] : 0.f;
      v[i] = f2bf(f);
    }
  }
  uint4 o;
  o.x = (unsigned)v[0] | ((unsigned)v[1] << 16);
  o.y = (unsigned)v[2] | ((unsigned)v[3] << 16);
  o.z = (unsigned)v[4] | ((unsigned)v[5] << 16);
  o.w = (unsigned)v[6] | ((unsigned)v[7] << 16);
  *reinterpret_cast<uint4*>(dst + e) = o;
}

struct PadJobs {
  const float* s[9];
  float* d[9];
  int ns[9];
  int nd[9];
};
__global__ __launch_bounds__(256) void pad_all_kernel(PadJobs pj) {
  const int job = blockIdx.y;
  const int i = blockIdx.x * 256 + threadIdx.x;
  if (i < pj.nd[job]) pj.d[job][i] = (i < pj.ns[job]) ? pj.s[job][i] : 0.f;
}

// ---------------- generic bf16 GEMM (128x128, 2-phase), dual-operand via blockIdx.z ----------------
template <int TANH, int OUT_BF16>
__global__ __launch_bounds__(256) void gemm_bt_kernel(
    const u16* __restrict__ A0, const u16* __restrict__ B0,
    const float* __restrict__ bias0, void* __restrict__ C0v, int K0,
    const u16* __restrict__ A1, const u16* __restrict__ B1,
    const float* __restrict__ bias1, void* __restrict__ C1v, int K1,
    int Nout, int Nfill, int ldc) {
  __shared__ u16 sA[128 * 32];
  __shared__ u16 sB[128 * 32];
  const int z = blockIdx.z;
  const u16* A = z ? A1 : A0;
  const u16* B = z ? B1 : B0;
  const float* bias = z ? bias1 : bias0;
  void* Cv = z ? C1v : C0v;
  const int K = z ? K1 : K0;
  const int tid = threadIdx.x;
  const int wid = tid >> 6;
  const int lane = tid & 63;
  const long long brow = (long long)blockIdx.y * 128;
  const long long bcol = (long long)blockIdx.x * 128;
  const int wr = (wid >> 1) * 64;
  const int wc = (wid & 1) * 64;
  const int lr = lane & 15;
  const int slot = lane >> 4;

  f32x4 acc[4][4];
#pragma unroll
  for (int i = 0; i < 4; ++i)
#pragma unroll
    for (int j = 0; j < 4; ++j)
#pragma unroll
      for (int q = 0; q < 4; ++q) acc[i][j][q] = 0.f;

  for (int k0 = 0; k0 < K; k0 += 32) {
    __syncthreads();
#pragma unroll
    for (int j = 0; j < 2; ++j) {
      const int c = j * 256 + tid;
      const int r = c >> 2;
      const int kc = ((c & 3) ^ ((r >> 1) & 3)) * 8;   // pre-swizzled source
      gload_lds16(A + (brow + r) * K + k0 + kc, sA + c * 8);
      gload_lds16(B + (bcol + r) * K + k0 + kc, sB + c * 8);
    }
    __syncthreads();
    b16x8 af[4], bfr[4];
#pragma unroll
    for (int i = 0; i < 4; ++i) {
      af[i]  = *reinterpret_cast<const b16x8*>(&sA[lds_off(wr + i * 16 + lr, slot)]);
      bfr[i] = *reinterpret_cast<const b16x8*>(&sB[lds_off(wc + i * 16 + lr, slot)]);
    }
#pragma unroll
    for (int i = 0; i < 4; ++i)
#pragma unroll
      for (int j = 0; j < 4; ++j)
        acc[i][j] = __builtin_amdgcn_mfma_f32_16x16x32_bf16(af[i], bfr[j], acc[i][j], 0, 0, 0);
  }

  const int rbase = wr + (lane >> 4) * 4;
#pragma unroll
  for (int i = 0; i < 4; ++i) {
#pragma unroll
    for (int j = 0; j < 4; ++j) {
      const long long col = bcol + wc + j * 16 + lr;
      if (col < Nfill) {
        const float bb = (col < Nout) ? bias[col] : 0.f;
#pragma unroll
        for (int q = 0; q < 4; ++q) {
          float v = acc[i][j][q] + bb;
          if (TANH) v = tanhf(v);
          if (col >= Nout) v = 0.f;
          const long long row = brow + rbase + i * 16 + q;
          if (OUT_BF16)
            reinterpret_cast<u16*>(Cv)[row * ldc + col] = f2bf(v);
          else
            reinterpret_cast<float*>(Cv)[row * ldc + col] = v;
        }
      }
    }
  }
}

// ---------------- 256x256 dual GEMM, 2 merged phases/K-tile, bf16 out ----------------
// C = A @ B^T + bias (bf16). blockIdx.z (post-swizzle) selects pair. Nout % 64 == 0.
// 8 waves (2M x 4N), BK=64, K-half-major LDS, dbuf, counted vmcnt(8), XCD swizzle.
// Staging pointers hoisted: pA/pA2/pB/pB2 advance +32 elems per stage call.
template <int TANH, int NTST>
__global__ __launch_bounds__(512, 2) void gemm256_dual_kernel(
    const u16* __restrict__ A0, const u16* __restrict__ Bg0,
    const float* __restrict__ bias0, u16* __restrict__ C0,
    const u16* __restrict__ A1, const u16* __restrict__ Bg1,
    const float* __restrict__ bias1, u16* __restrict__ C1,
    int K, int Nout, int ldc) {
  __shared__ u16 sAB[65536];
  const int tid = threadIdx.x;
  const int lane = tid & 63;
  const int wid = tid >> 6;
  const int wm = wid >> 2;
  const int wn = wid & 3;

  // XCD-aware bijective swizzle (nwg % 8 == 0 by construction).
  const int gy = gridDim.y;
  const int nwg = 16 * gy * gridDim.z;
  int flat = blockIdx.x + 16 * (blockIdx.y + gy * blockIdx.z);
  flat = (flat & 7) * (nwg >> 3) + (flat >> 3);
  const int m = flat & 15;
  const int rest = flat >> 4;
  const int n = rest % gy;
  const int z = rest / gy;

  const long long brow = (long long)m * 256;
  const long long bcol = (long long)n * 256;
  const u16* Ag = z ? A1 : A0;
  const u16* Bg = z ? Bg1 : Bg0;
  const float* bias = z ? bias1 : bias0;
  u16* C = z ? C1 : C0;
  const int nt = K >> 6;

  // hoisted per-thread staging pointers: stage k-offsets are 0,32,64,... (+32/call)
  const int srow = tid >> 2;                                   // 0..127
  const int scol = ((tid & 3) ^ ((srow >> 1) & 3)) << 3;       // pre-swizzled source slot
  const u16* pA  = Ag + (brow + srow) * (long long)K + scol;
  const u16* pA2 = pA + (long long)128 * K;
  const u16* pB  = Bg + (bcol + srow) * (long long)K + scol;
  const u16* pB2 = pB + (long long)128 * K;

  auto stageA = [&](int buf, int kh) {
    u16* l = &sAB[buf * 16384 + kh * 8192 + tid * 8];
    gload_lds16(pA, l);
    gload_lds16(pA2, l + 4096);
    pA += 32; pA2 += 32;
  };
  auto stageB = [&](int buf, int kh) {
    u16* l = &sAB[32768 + buf * 16384 + kh * 8192 + tid * 8];
    gload_lds16(pB, l);
    gload_lds16(pB2, l + 4096);
    pB += 32; pB2 += 32;
  };
  auto rdA = [&](int buf, int fr, int ksub) {
    const int row = wm * 128 + fr * 16 + (lane & 15);
    return *reinterpret_cast<const b16x8*>(
        &sAB[buf * 16384 + ksub * 8192 + lds_off(row, lane >> 4)]);
  };
  auto rdB = [&](int buf, int fj, int ksub) {
    const int row = wn * 64 + fj * 16 + (lane & 15);
    return *reinterpret_cast<const b16x8*>(
        &sAB[32768 + buf * 16384 + ksub * 8192 + lds_off(row, lane >> 4)]);
  };

  f32x4 acc[8][4];
#pragma unroll
  for (int i = 0; i < 8; ++i)
#pragma unroll
    for (int j = 0; j < 4; ++j)
#pragma unroll
      for (int q = 0; q < 4; ++q) acc[i][j][q] = 0.f;

  // prologue: tile0 fully + tile1 khalf0; wait for tile0 (8 oldest of 12).
  // stage k-sequence: A: 0,32,64 ; B: 0,32,64  (pointers advance +32 each call)
  stageA(0, 0); stageB(0, 0);
  stageA(0, 1); stageB(0, 1);
  stageA(1, 0); stageB(1, 0);
  asm volatile("s_waitcnt vmcnt(4)" ::: "memory");
  __builtin_amdgcn_s_barrier();

  b16x8 af[8], bf[4];
  for (int t = 0; t < nt; ++t) {
    const int cur = t & 1;
    if (t + 1 == nt) {  // final tile: no more prefetch -> drain everything.
      asm volatile("s_waitcnt vmcnt(0)" ::: "memory");
      __builtin_amdgcn_s_barrier();
    }
    // ---- phase A: all rows, ksub 0 ----
#pragma unroll
    for (int j = 0; j < 4; ++j) bf[j] = rdB(cur, j, 0);
#pragma unroll
    for (int i = 0; i < 8; ++i) af[i] = rdA(cur, i, 0);
    if (t + 1 < nt) {
      stageA(cur ^ 1, 1);                             // A-kh1(t+1)
      stageB(cur ^ 1, 1);                             // B-kh1(t+1)
    }
    __builtin_amdgcn_s_barrier();
    __builtin_amdgcn_s_setprio(1);
#pragma unroll
    for (int i = 0; i < 8; ++i)
#pragma unroll
      for (int j = 0; j < 4; ++j)
        acc[i][j] = __builtin_amdgcn_mfma_f32_16x16x32_bf16(af[i], bf[j], acc[i][j], 0, 0, 0);
    __builtin_amdgcn_s_setprio(0);
    asm volatile("s_waitcnt vmcnt(8)" ::: "memory");  // kh1(t) (staged (t-1)phA) complete
    __builtin_amdgcn_s_barrier();
    // ---- phase B: all rows, ksub 1 ----
#pragma unroll
    for (int j = 0; j < 4; ++j) bf[j] = rdB(cur, j, 1);
#pragma unroll
    for (int i = 0; i < 8; ++i) af[i] = rdA(cur, i, 1);
    if (t + 2 < nt) {
      stageA(cur, 0);                                 // A-kh0(t+2)
      stageB(cur, 0);                                 // B-kh0(t+2)
    }
    __builtin_amdgcn_s_barrier();
    __builtin_amdgcn_s_setprio(1);
#pragma unroll
    for (int i = 0; i < 8; ++i)
#pragma unroll
      for (int j = 0; j < 4; ++j)
        acc[i][j] = __builtin_amdgcn_mfma_f32_16x16x32_bf16(af[i], bf[j], acc[i][j], 0, 0, 0);
    __builtin_amdgcn_s_setprio(0);
    asm volatile("s_waitcnt vmcnt(8)" ::: "memory");  // kh0(t+1) (staged (t-1)phB) complete
    __builtin_amdgcn_s_barrier();
  }

  // epilogue: per-wave padded LDS bounce (stride 68 f32) -> bf16 full-line stores.
  __syncthreads();
  const long long gcb = bcol + wn * 64;
  float* lp = reinterpret_cast<float*>(sAB) + wid * 1104;
  if (gcb < Nout) {
    float bv4[4];
#pragma unroll
    for (int j = 0; j < 4; ++j) bv4[j] = bias[gcb + j * 16 + (lane & 15)];
#pragma unroll
    for (int fr = 0; fr < 8; ++fr) {
#pragma unroll
      for (int j = 0; j < 4; ++j)
#pragma unroll
        for (int q = 0; q < 4; ++q)
          lp[((lane >> 4) * 4 + q) * 68 + j * 16 + (lane & 15)] = acc[fr][j][q] + bv4[j];
#pragma unroll
      for (int p = 0; p < 2; ++p) {
        const int row = p * 8 + (lane >> 3);
        float f[8];
        *reinterpret_cast<float4*>(&f[0]) =
            *reinterpret_cast<const float4*>(&lp[row * 68 + (lane & 7) * 8]);
        *reinterpret_cast<float4*>(&f[4]) =
            *reinterpret_cast<const float4*>(&lp[row * 68 + (lane & 7) * 8 + 4]);
        if (TANH) {
#pragma unroll
          for (int k = 0; k < 8; ++k) f[k] = tanhf(f[k]);
        }
        u32x4 o;
        o.x = (unsigned)f2bf(f[0]) | ((unsigned)f2bf(f[1]) << 16);
        o.y = (unsigned)f2bf(f[2]) | ((unsigned)f2bf(f[3]) << 16);
        o.z = (unsigned)f2bf(f[4]) | ((unsigned)f2bf(f[5]) << 16);
        o.w = (unsigned)f2bf(f[6]) | ((unsigned)f2bf(f[7]) << 16);
        const long long grow = brow + wm * 128 + fr * 16 + row;
        u32x4* dst = reinterpret_cast<u32x4*>(&C[grow * ldc + gcb + (lane & 7) * 8]);
        if (NTST)
          __builtin_nontemporal_store(o, dst);
        else
          *dst = o;
      }
    }
  }
}

// ---------------- rank product + partial sum (bf16 M inputs, NT loads) ----------------
// EMITB: final chunk — z = ZF_prev + acc, emitted directly as bf16 into ZB.
template <int FIRST, int EMITB>
__global__ __launch_bounds__(256) void rank_mul_kernel(
    const u16* __restrict__ M0, const u16* __restrict__ M1,
    float* __restrict__ ZF, u16* __restrict__ ZB, int rc, int ldm) {
  const int idx = blockIdx.x * 256 + threadIdx.x;     // 4096*200 threads
  const int b = idx / 200;
  const int d0 = (idx - b * 200) * 8;
  const u16* p0 = M0 + (long long)b * ldm + d0;
  const u16* p1 = M1 + (long long)b * ldm + d0;
  float acc[8];
#pragma unroll
  for (int i = 0; i < 8; ++i) acc[i] = 0.f;
  for (int r = 0; r < rc; ++r) {
    const u32x4 a = __builtin_nontemporal_load(reinterpret_cast<const u32x4*>(p0 + r * 1600));
    const u32x4 c = __builtin_nontemporal_load(reinterpret_cast<const u32x4*>(p1 + r * 1600));
    const unsigned aw[4] = {a.x, a.y, a.z, a.w};
    const unsigned cw[4] = {c.x, c.y, c.z, c.w};
#pragma unroll
    for (int k = 0; k < 4; ++k) {
      acc[2 * k]     += bf2f((u16)(aw[k] & 0xffff)) * bf2f((u16)(cw[k] & 0xffff));
      acc[2 * k + 1] += bf2f((u16)(aw[k] >> 16))    * bf2f((u16)(cw[k] >> 16));
    }
  }
  float* zf = ZF + (long long)b * 1600 + d0;
  if (EMITB) {
#pragma unroll
    for (int i = 0; i < 8; ++i) acc[i] += zf[i];
    uint4 o;
    o.x = (unsigned)f2bf(acc[0]) | ((unsigned)f2bf(acc[1]) << 16);
    o.y = (unsigned)f2bf(acc[2]) | ((unsigned)f2bf(acc[3]) << 16);
    o.z = (unsigned)f2bf(acc[4]) | ((unsigned)f2bf(acc[5]) << 16);
    o.w = (unsigned)f2bf(acc[6]) | ((unsigned)f2bf(acc[7]) << 16);
    *reinterpret_cast<uint4*>(ZB + (long long)b * 1600 + d0) = o;
  } else if (FIRST) {
#pragma unroll
    for (int i = 0; i < 8; ++i) zf[i] = acc[i];
  } else {
#pragma unroll
    for (int i = 0; i < 8; ++i) zf[i] += acc[i];
  }
}

// ---------------- per-row head: layer2 + slice/mask assembly ----------------
__global__ __launch_bounds__(256) void head_kernel(
    const float* __restrict__ T, const int* __restrict__ qtype,
    const float* __restrict__ W20, const float* __restrict__ b20,
    const float* __restrict__ W21, const float* __restrict__ b21,
    const float* __restrict__ W22, const float* __restrict__ b22,
    const float* __restrict__ W23, const float* __restrict__ b23,
    float* __restrict__ out) {
  const int b = blockIdx.x * 4 + (threadIdx.x >> 6);
  const int lane = threadIdx.x & 63;
  const int qt = qtype[b];
  const float* W2 = (qt == 0) ? W20 : (qt == 1) ? W21 : (qt == 2) ? W22 : W23;
  const float* b2 = (qt == 0) ? b20 : (qt == 1) ? b21 : (qt == 2) ? b22 : b23;
  const int lo = (qt == 2) ? 2 : (qt == 3) ? 7 : 0;
  const int hi = (qt == 3) ? 95 : (qt == 2) ? 7 : 2;
  const float* trow = T + (long long)b * 1024 + qt * 256;
  for (int c = lane; c < 95; c += 64) {
    float v = 0.f;
    if (c >= lo && c < hi) {
      const int jj = c - lo;
      const float* w = W2 + jj * 256;
      float acc = b2[jj];
      for (int k = 0; k < 256; k += 4) {
        const float4 tv = *reinterpret_cast<const float4*>(trow + k);
        const float4 wv = *reinterpret_cast<const float4*>(w + k);
        acc += tv.x * wv.x + tv.y * wv.y + tv.z * wv.z + tv.w * wv.w;
      }
      v = acc;
    }
    out[(long long)b * 95 + c] = v;
  }
}

// ---------------- launch ----------------

extern "C" void kernel_launch(void* const* d_in, const int* in_sizes, int n_in,
                              void* d_out, int out_size, void* d_ws, size_t ws_size,
                              hipStream_t stream) {
  (void)in_sizes; (void)n_in; (void)out_size; (void)ws_size;
  const float* input_v = (const float*)d_in[0];
  const float* input_q = (const float*)d_in[1];
  const int*   qtype   = (const int*)d_in[2];
  const float* Wv  = (const float*)d_in[3];  const float* bv  = (const float*)d_in[4];
  const float* Wq  = (const float*)d_in[5];  const float* bq  = (const float*)d_in[6];
  const float* W0  = (const float*)d_in[7];  const float* b0  = (const float*)d_in[8];
  const float* W1  = (const float*)d_in[9];  const float* b1  = (const float*)d_in[10];
  const float* Wm0 = (const float*)d_in[11]; const float* bm0 = (const float*)d_in[12];
  const float* Wm1 = (const float*)d_in[13]; const float* bm1 = (const float*)d_in[14];
  const float* Wo  = (const float*)d_in[15]; const float* bo  = (const float*)d_in[16];
  const float* cW1[4] = {(const float*)d_in[17], (const float*)d_in[21],
                         (const float*)d_in[25], (const float*)d_in[29]};
  const float* cb1[4] = {(const float*)d_in[18], (const float*)d_in[22],
                         (const float*)d_in[26], (const float*)d_in[30]};
  const float* cW2[4] = {(const float*)d_in[19], (const float*)d_in[23],
                         (const float*)d_in[27], (const float*)d_in[31]};
  const float* cb2[4] = {(const float*)d_in[20], (const float*)d_in[24],
                         (const float*)d_in[28], (const float*)d_in[32]};

  char* ws = (char*)d_ws;
  // Persistent across stage 4: H0, H1, ZF.
  u16*   H0  = (u16*)(ws + 0);           // [4096,1600] bf16
  u16*   H1  = (u16*)(ws + 13107200);    // [4096,1600] bf16
  float* ZF  = (float*)(ws + 26214400);  // [4096,1600] f32 accumulator
  char*  S   = ws + 52428800;            // overlay region
  // stages 1-3
  u16*   XV  = (u16*)(S + 0);            // [4096,1216]
  u16*   XQ  = (u16*)(S + 9961472);      // [4096,1216]
  char*  S3  = S + 19922944;             // cvt buffers
  // stage 4 chunk buffers (XV/XQ dead by then): 5-rank chunks (cols=8000, pad 8192)
  u16*   WMC0 = (u16*)(S + 0);           // [8192,1600] bf16 = 26.2 MB
  u16*   WMC1 = (u16*)(S + 26214400);
  u16*   M0C  = (u16*)(S + 52428800);    // [4096,8000] bf16 = 65.5 MB
  u16*   M1C  = (u16*)(S + 117964800);   // ends S+183,500,800 = ws+235.93 MB
  // stages 5-7
  u16*   ZB  = (u16*)(S + 0);            // [4096,1600] bf16
  u16*   XB  = (u16*)(S + 13107200);     // [4096,1216] bf16
  float* TB  = (float*)(S + 23068672);   // [4096,1024] f32
  char*  S5  = S + 39845888;
  // biases (above stage-4 overlay; ws usage ends < 236.15 MB, proven safe 239.6 MB)
  float* BVP = (float*)(ws + 236100000); // [1280]
  float* BQP = (float*)(ws + 236105120);
  float* B0P = (float*)(ws + 236110240); // [1664]
  float* B1P = (float*)(ws + 236116896);
  float* BOP = (float*)(ws + 236123552); // [1280]
  float* B1C = (float*)(ws + 236128672); // [1024]

  const dim3 blk(256);
  auto blocks8 = [](long long n, int kd) {  // grid.x for one cvt job
    return (unsigned)((((long long)n * kd) >> 3) + 255) / 256;
  };
  auto cvt2 = [&](const float* s0, u16* d0, int Ns0, int Ks0, int Nd0, int Kd0,
                  const float* s1, u16* d1, int Ns1, int Ks1, int Nd1, int Kd1) {
    CvtJobs J;
    J.s[0] = s0; J.d[0] = d0; J.Ns[0] = Ns0; J.Ks[0] = Ks0; J.Nd[0] = Nd0; J.Kd[0] = Kd0;
    J.s[1] = s1; J.d[1] = d1; J.Ns[1] = Ns1; J.Ks[1] = Ks1; J.Nd[1] = Nd1; J.Kd[1] = Kd1;
    J.s[2] = s1; J.d[2] = d1; J.Ns[2] = 0; J.Ks[2] = Ks1; J.Nd[2] = 0; J.Kd[2] = Kd1;
    J.s[3] = J.s[2]; J.d[3] = J.d[2]; J.Ns[3] = 0; J.Ks[3] = Ks1; J.Nd[3] = 0; J.Kd[3] = Kd1;
    unsigned gx = blocks8(Nd0, Kd0);
    unsigned gx1 = blocks8(Nd1, Kd1);
    if (gx1 > gx) gx = gx1;
    cvtN_kernel<<<dim3(gx, 2), blk, 0, stream>>>(J);
  };

  // all bias pads in one launch
  {
    PadJobs pj;
    const float* ss[9] = {bv, bq, b0, b1, bo, cb1[0], cb1[1], cb1[2], cb1[3]};
    float* dd[9] = {BVP, BQP, B0P, B1P, BOP, B1C, B1C + 256, B1C + 512, B1C + 768};
    int nss[9] = {1200, 1200, 1600, 1600, 1200, 256, 256, 256, 256};
    int ndd[9] = {1280, 1280, 1664, 1664, 1280, 256, 256, 256, 256};
    for (int i = 0; i < 9; ++i) { pj.s[i] = ss[i]; pj.d[i] = dd[i]; pj.ns[i] = nss[i]; pj.nd[i] = ndd[i]; }
    pad_all_kernel<<<dim3(7, 9), blk, 0, stream>>>(pj);
  }

  // stages 1+2 fused: x_v = tanh(input_v @ Wv^T + bv); x_q = tanh(input_q @ Wq^T + bq)
  {
    u16* INV = (u16*)S3;                     // [4096,768]
    u16* WVB = (u16*)(S3 + 6291456);         // [1280,768]
    u16* INQ = (u16*)(S3 + 8257536);         // [4096,2400] (19.66 MB)
    u16* WQB = (u16*)(S3 + 27918336);        // [1280,2400] (6.14 MB; ends S3+34.06MB)
    cvt2(input_v, INV, 4096, 768, 4096, 768,
         input_q, INQ, 4096, 2400, 4096, 2400);
    cvt2(Wv, WVB, 1200, 768, 1280, 768,
         Wq, WQB, 1200, 2400, 1280, 2400);
    gemm_bt_kernel<1, 1><<<dim3(10, 32, 2), blk, 0, stream>>>(
        INV, WVB, BVP, XV, 768,
        INQ, WQB, BQP, XQ, 2400, 1200, 1216, 1216);
  }
  // stage 3: h0 = x_v @ W0^T + b0 ; h1 = x_q @ W1^T + b1  (256^2 dual, K=1216, nt=19)
  {
    u16* W0B = (u16*)S3;                     // [1792,1216]
    u16* W1B = (u16*)(S3 + 4358144);
    cvt2(W0, W0B, 1600, 1200, 1792, 1216,
         W1, W1B, 1600, 1200, 1792, 1216);
    gemm256_dual_kernel<0, 0><<<dim3(16, 7, 2), dim3(512), 0, stream>>>(
        XV, W0B, B0P, H0, XQ, W1B, B1P, H1, 1216, 1600, 1600);
  }
  // stage 4: Mutan via 3 chunks x 5 ranks (cols=8000, NB=32 -> 1024 blocks = 4 full rounds).
  for (int c = 0; c < 3; ++c) {
    const int cols = 8000;
    const int NB = 32;                       // pad to 8192
    const int rowsPad = 8192;
    const long long roff = (long long)c * 8000;
    cvt2(Wm0 + roff * 1600, WMC0, cols, 1600, rowsPad, 1600,
         Wm1 + roff * 1600, WMC1, cols, 1600, rowsPad, 1600);
    gemm256_dual_kernel<0, 1><<<dim3(16, NB, 2), dim3(512), 0, stream>>>(
        H0, WMC0, bm0 + roff, M0C, H1, WMC1, bm1 + roff, M1C, 1600, cols, cols);
    if (c == 0)
      rank_mul_kernel<1, 0><<<dim3(3200), blk, 0, stream>>>(M0C, M1C, ZF, ZB, 5, cols);
    else if (c == 1)
      rank_mul_kernel<0, 0><<<dim3(3200), blk, 0, stream>>>(M0C, M1C, ZF, ZB, 5, cols);
    else
      rank_mul_kernel<0, 1><<<dim3(3200), blk, 0, stream>>>(M0C, M1C, ZF, ZB, 5, cols);
  }
  // stage 5: x = z @ Wo^T + bo
  {
    u16* WOB = (u16*)S5;                     // [1280,1600]
    cvt2(Wo, WOB, 1200, 1600, 1280, 1600,
         Wo, WOB, 0, 1600, 0, 1600);         // job1 degenerate (0 rows)
    gemm_bt_kernel<0, 1><<<dim3(10, 32, 1), blk, 0, stream>>>(
        ZB, WOB, BOP, XB, 1600,
        ZB, WOB, BOP, XB, 1600, 1200, 1216, 1216);
  }
  // stage 6: t = tanh(x @ cW1cat^T + b1cat), all 4 heads batched (N=1024)
  {
    u16* CW1B = (u16*)S5;                    // [1024,1216]
    CvtJobs J;
    for (int qt = 0; qt < 4; ++qt) {
      J.s[qt] = cW1[qt];
      J.d[qt] = CW1B + (long long)qt * 256 * 1216;
      J.Ns[qt] = 256; J.Ks[qt] = 1200; J.Nd[qt] = 256; J.Kd[qt] = 1216;
    }
    cvtN_kernel<<<dim3(blocks8(256, 1216), 4), blk, 0, stream>>>(J);
    gemm_bt_kernel<1, 0><<<dim3(8, 32, 1), blk, 0, stream>>>(
        XB, CW1B, B1C, TB, 1216,
        XB, CW1B, B1C, TB, 1216, 1024, 1024, 1024);
  }
  // stage 7: layer2 + assemble final [4096,95]
  head_kernel<<<dim3(1024), blk, 0, stream>>>(TB, qtype,
      cW2[0], cb2[0], cW2[1], cb2[1], cW2[2], cb2[2], cW2[3], cb2[3],
      (float*)d_out);
}